// Round 4
// baseline (134.375 us; speedup 1.0000x reference)
//
#include <hip/hip_runtime.h>
#include <hip/hip_bf16.h>
#include <stdint.h>

#define BB   8
#define CIN  256
#define COUT 128
#define NN   4096

using f32x4  = __attribute__((ext_vector_type(4))) float;
using bf16x8 = __attribute__((ext_vector_type(8))) __bf16;
using u16x8  = __attribute__((ext_vector_type(8))) unsigned short;

static __device__ __forceinline__ unsigned short f2bf(float f) {
    unsigned int u = __builtin_bit_cast(unsigned int, f);
    u += 0x7FFFu + ((u >> 16) & 1u);
    return (unsigned short)(u >> 16);
}
static __device__ __forceinline__ float bf2f(unsigned short u) {
    return __builtin_bit_cast(float, (unsigned int)u << 16);
}
static __device__ __forceinline__ ushort4 pack4(float a, float b, float c, float d) {
    ushort4 r; r.x=f2bf(a); r.y=f2bf(b); r.z=f2bf(c); r.w=f2bf(d); return r;
}
#define MFMA(a,b,c) __builtin_amdgcn_mfma_f32_16x16x32_bf16((a),(b),(c),0,0,0)

// ================= kA: per-batch Gram partials Sp[bid] = X_chunk X_chunk^T, row-sum partials =================
__global__ __launch_bounds__(512) void kA_gram(
    const float* __restrict__ x, float* __restrict__ Sp, float* __restrict__ Rp)
{
    __shared__ __align__(16) unsigned short Xs[256*256];   // 128 KB, [c][n] swizzled
    int bid = blockIdx.x;
    int b = bid >> 4, ch = bid & 15;
    int n0 = ch * 256;
    int t = threadIdx.x, lane = t & 63, wv = t >> 6;

    const float* xb = x + (size_t)b*CIN*NN + n0;
    #pragma unroll
    for (int i = 0; i < 32; ++i) {
        int c = wv*32 + i;
        float4 f = *(const float4*)(xb + (size_t)c*NN + lane*4);
        float s = f.x + f.y + f.z + f.w;
        #pragma unroll
        for (int off = 1; off < 64; off <<= 1) s += __shfl_xor(s, off);
        if (lane == 0) Rp[bid*256 + c] = s;
        *(ushort4*)&Xs[(c*256 + lane*4) ^ ((c&7)<<3)] = pack4(f.x, f.y, f.z, f.w);
    }
    __syncthreads();

    int wr = wv >> 1, wc = wv & 1;          // 4 x 2 wave grid: tile 64c1 x 128c2
    int lr = lane & 15, lg = lane >> 4;
    f32x4 acc[4][8];
    #pragma unroll
    for (int i = 0; i < 4; ++i)
        #pragma unroll
        for (int j = 0; j < 8; ++j) acc[i][j] = (f32x4){0.f,0.f,0.f,0.f};

    #pragma unroll
    for (int ks = 0; ks < 8; ++ks) {
        bf16x8 af[4], bfr[8];
        #pragma unroll
        for (int mi = 0; mi < 4; ++mi) {
            int row = wr*64 + mi*16 + lr;
            af[mi] = __builtin_bit_cast(bf16x8, *(const u16x8*)&Xs[(row*256 + ks*32 + lg*8) ^ ((row&7)<<3)]);
        }
        #pragma unroll
        for (int ni = 0; ni < 8; ++ni) {
            int row = wc*128 + ni*16 + lr;
            bfr[ni] = __builtin_bit_cast(bf16x8, *(const u16x8*)&Xs[(row*256 + ks*32 + lg*8) ^ ((row&7)<<3)]);
        }
        #pragma unroll
        for (int mi = 0; mi < 4; ++mi)
            #pragma unroll
            for (int ni = 0; ni < 8; ++ni)
                acc[mi][ni] = MFMA(af[mi], bfr[ni], acc[mi][ni]);
    }

    float* dst = Sp + (size_t)bid * 65536;
    #pragma unroll
    for (int mi = 0; mi < 4; ++mi)
        #pragma unroll
        for (int ni = 0; ni < 8; ++ni)
            #pragma unroll
            for (int j = 0; j < 4; ++j) {
                int c1 = wr*64 + mi*16 + lg*4 + j;
                int c2 = wc*128 + ni*16 + lr;
                dst[c1*256 + c2] = acc[mi][ni][j];
            }
}

// ================= kR: reduce partials -> Sbf bf16, r fp32; pack weights bf16; zero stats =================
__global__ __launch_bounds__(256) void kR(
    const float* __restrict__ Sp, const float* __restrict__ Rp,
    const float* __restrict__ pw, const float* __restrict__ gw,
    const float* __restrict__ tw, const float* __restrict__ Www,
    unsigned short* __restrict__ Sbf, float* __restrict__ rv,
    unsigned short* __restrict__ Pwb, unsigned short* __restrict__ Gwb,
    unsigned short* __restrict__ TwT, unsigned short* __restrict__ Wwb,
    float* __restrict__ stats)
{
    int blk = blockIdx.x, t = threadIdx.x;
    if (blk < 128) {
        int b = blk >> 4, part = blk & 15;
        int base = part * 4096;
        #pragma unroll
        for (int i4 = t; i4 < 1024; i4 += 256) {
            float4 s = {0.f,0.f,0.f,0.f};
            #pragma unroll
            for (int p = 0; p < 16; ++p) {
                float4 v = *(const float4*)(Sp + (size_t)(b*16+p)*65536 + base + i4*4);
                s.x += v.x; s.y += v.y; s.z += v.z; s.w += v.w;
            }
            *(ushort4*)(Sbf + (size_t)b*65536 + base + i4*4) = pack4(s.x, s.y, s.z, s.w);
        }
    } else if (blk < 136) {
        int b = blk - 128;
        float s = 0.f;
        #pragma unroll
        for (int p = 0; p < 16; ++p) s += Rp[(b*16+p)*256 + t];
        rv[b*256 + t] = s;
    } else {
        int j = (blk - 136)*256 + t;                 // 0..2047
        for (int i = j; i < 32768; i += 2048) {
            Pwb[i] = f2bf(pw[i]);
            Gwb[i] = f2bf(gw[i]);
            Wwb[i] = f2bf(Www[i]);
            int c = i >> 7, k = i & 127;
            TwT[i] = f2bf(tw[k*256 + c]);
        }
        if (blk == 136) stats[t] = 0.f;
        if (blk == 137) stats[256 + t] = 0.f;
    }
}

// ================= kB12: per-batch chain  T1=Pw S; M=T1 Gw^T + rank1; W2=Ww M^T/N; E=W2 Tw; f=W2 tb+Wb ====
__global__ __launch_bounds__(512) void kB12(
    const unsigned short* __restrict__ Sbf, const float* __restrict__ rv,
    const float* __restrict__ pwf, const float* __restrict__ gwf,
    const unsigned short* __restrict__ Pwb, const unsigned short* __restrict__ Gwb,
    const unsigned short* __restrict__ TwT, const unsigned short* __restrict__ Wwb,
    const float* __restrict__ gbv, const float* __restrict__ pbv,
    const float* __restrict__ tbv, const float* __restrict__ Wbv,
    unsigned short* __restrict__ Ebf, float* __restrict__ fv)
{
    __shared__ __align__(16) unsigned short Ss[128*256];    // 64 KB: S-half, later W2[256][128]
    __shared__ __align__(16) unsigned short Tbuf[128*128];  // 32 KB: T1-half, later M
    __shared__ float u_l[128], v_l[128], pb_l[128], gb_l[128];
    int b = blockIdx.x, t = threadIdx.x, lane = t & 63, wv = t >> 6;
    int lr = lane & 15, lg = lane >> 4;
    const unsigned short* Sb = Sbf + (size_t)b*65536;
    const float* rb = rv + b*256;

    // P0: u = Pw r, v = Gw r
    if (t < 128) {
        float s = 0.f;
        for (int c = 0; c < 256; ++c) s += pwf[t*256 + c] * rb[c];
        u_l[t] = s; pb_l[t] = pbv[t];
    } else if (t < 256) {
        int k = t - 128;
        float s = 0.f;
        for (int c = 0; c < 256; ++c) s += gwf[k*256 + c] * rb[c];
        v_l[k] = s; gb_l[k] = gbv[k];
    }

    int wrM = wv >> 2, wcM = wv & 3;   // 2x4 grid: M tile 64k x 32c
    f32x4 accM[4][2];
    #pragma unroll
    for (int i = 0; i < 4; ++i) { accM[i][0] = (f32x4){0,0,0,0}; accM[i][1] = (f32x4){0,0,0,0}; }

    for (int h = 0; h < 2; ++h) {
        __syncthreads();
        // stage S rows [h*128, h*128+128) x [0,256)
        for (int i = t; i < 4096; i += 512) {
            int row = i >> 5, c8 = (i & 31) * 8;
            u16x8 vv = *(const u16x8*)(Sb + (size_t)(h*128 + row)*256 + c8);
            *(u16x8*)&Ss[(row*256 + c8) ^ ((row&7)<<3)] = vv;
        }
        __syncthreads();
        // T1_h[k][c2l] = sum_c1 Pw[k,c1] S[c2,c1]   (S symmetric -> row c2)
        f32x4 accT[4][2];
        #pragma unroll
        for (int i = 0; i < 4; ++i) { accT[i][0] = (f32x4){0,0,0,0}; accT[i][1] = (f32x4){0,0,0,0}; }
        #pragma unroll
        for (int ks = 0; ks < 8; ++ks) {
            bf16x8 a4[4], b2[2];
            #pragma unroll
            for (int mi = 0; mi < 4; ++mi) {
                int k = wrM*64 + mi*16 + lr;
                a4[mi] = __builtin_bit_cast(bf16x8, *(const u16x8*)(Pwb + (size_t)k*256 + ks*32 + lg*8));
            }
            #pragma unroll
            for (int ni = 0; ni < 2; ++ni) {
                int c2l = wcM*32 + ni*16 + lr;
                b2[ni] = __builtin_bit_cast(bf16x8, *(const u16x8*)&Ss[(c2l*256 + ks*32 + lg*8) ^ ((c2l&7)<<3)]);
            }
            #pragma unroll
            for (int mi = 0; mi < 4; ++mi)
                #pragma unroll
                for (int ni = 0; ni < 2; ++ni)
                    accT[mi][ni] = MFMA(a4[mi], b2[ni], accT[mi][ni]);
        }
        __syncthreads();
        #pragma unroll
        for (int mi = 0; mi < 4; ++mi)
            #pragma unroll
            for (int ni = 0; ni < 2; ++ni)
                #pragma unroll
                for (int j = 0; j < 4; ++j) {
                    int k = wrM*64 + mi*16 + lg*4 + j;
                    int c2l = wcM*32 + ni*16 + lr;
                    Tbuf[(k*128 + c2l) ^ ((k&7)<<3)] = f2bf(accT[mi][ni][j]);
                }
        __syncthreads();
        // M += T1_h * Gw[:, h*128..]^T
        #pragma unroll
        for (int ks = 0; ks < 4; ++ks) {
            bf16x8 a4[4], b2[2];
            #pragma unroll
            for (int mi = 0; mi < 4; ++mi) {
                int k = wrM*64 + mi*16 + lr;
                a4[mi] = __builtin_bit_cast(bf16x8, *(const u16x8*)&Tbuf[(k*128 + ks*32 + lg*8) ^ ((k&7)<<3)]);
            }
            #pragma unroll
            for (int ni = 0; ni < 2; ++ni) {
                int c = wcM*32 + ni*16 + lr;
                b2[ni] = __builtin_bit_cast(bf16x8, *(const u16x8*)(Gwb + (size_t)c*256 + h*128 + ks*32 + lg*8));
            }
            #pragma unroll
            for (int mi = 0; mi < 4; ++mi)
                #pragma unroll
                for (int ni = 0; ni < 2; ++ni)
                    accM[mi][ni] = MFMA(a4[mi], b2[ni], accM[mi][ni]);
        }
    }
    __syncthreads();
    // M + rank-1 terms -> Tbuf
    #pragma unroll
    for (int mi = 0; mi < 4; ++mi)
        #pragma unroll
        for (int ni = 0; ni < 2; ++ni)
            #pragma unroll
            for (int j = 0; j < 4; ++j) {
                int k = wrM*64 + mi*16 + lg*4 + j;
                int c = wcM*32 + ni*16 + lr;
                float val = accM[mi][ni][j] + u_l[k]*gb_l[c] + pb_l[k]*v_l[c] + 4096.0f*pb_l[k]*gb_l[c];
                Tbuf[(k*128 + c) ^ ((k&7)<<3)] = f2bf(val);
            }
    __syncthreads();
    // W2[o][kk] = (1/N) sum_c Ww[o,c] M[kk,c]   : 4x2 grid, tile 64o x 64k
    int wrW = wv >> 1, wcW = wv & 1;
    f32x4 accW[4][4];
    #pragma unroll
    for (int i = 0; i < 4; ++i)
        #pragma unroll
        for (int j = 0; j < 4; ++j) accW[i][j] = (f32x4){0,0,0,0};
    #pragma unroll
    for (int ks = 0; ks < 4; ++ks) {
        bf16x8 a4[4], b4[4];
        #pragma unroll
        for (int mi = 0; mi < 4; ++mi) {
            int o = wrW*64 + mi*16 + lr;
            a4[mi] = __builtin_bit_cast(bf16x8, *(const u16x8*)(Wwb + (size_t)o*128 + ks*32 + lg*8));
        }
        #pragma unroll
        for (int ni = 0; ni < 4; ++ni) {
            int kk = wcW*64 + ni*16 + lr;
            b4[ni] = __builtin_bit_cast(bf16x8, *(const u16x8*)&Tbuf[(kk*128 + ks*32 + lg*8) ^ ((kk&7)<<3)]);
        }
        #pragma unroll
        for (int mi = 0; mi < 4; ++mi)
            #pragma unroll
            for (int ni = 0; ni < 4; ++ni)
                accW[mi][ni] = MFMA(a4[mi], b4[ni], accW[mi][ni]);
    }
    __syncthreads();   // Ss (S-half) dead; write W2 into Ss
    #pragma unroll
    for (int mi = 0; mi < 4; ++mi)
        #pragma unroll
        for (int ni = 0; ni < 4; ++ni)
            #pragma unroll
            for (int j = 0; j < 4; ++j) {
                int o = wrW*64 + mi*16 + lg*4 + j;
                int kk = wcW*64 + ni*16 + lr;
                Ss[(o*128 + kk) ^ ((o&7)<<3)] = f2bf(accW[mi][ni][j] * (1.0f/4096.0f));
            }
    __syncthreads();
    // E[o][c'] = sum_kk W2[o,kk] TwT[c',kk]  : 4x2 grid, tile 64o x 128c'
    f32x4 accE[4][8];
    #pragma unroll
    for (int i = 0; i < 4; ++i)
        #pragma unroll
        for (int j = 0; j < 8; ++j) accE[i][j] = (f32x4){0,0,0,0};
    #pragma unroll
    for (int ks = 0; ks < 4; ++ks) {
        bf16x8 a4[4], b8[8];
        #pragma unroll
        for (int mi = 0; mi < 4; ++mi) {
            int o = wrW*64 + mi*16 + lr;
            a4[mi] = __builtin_bit_cast(bf16x8, *(const u16x8*)&Ss[(o*128 + ks*32 + lg*8) ^ ((o&7)<<3)]);
        }
        #pragma unroll
        for (int ni = 0; ni < 8; ++ni) {
            int cp = wcW*128 + ni*16 + lr;
            b8[ni] = __builtin_bit_cast(bf16x8, *(const u16x8*)(TwT + (size_t)cp*128 + ks*32 + lg*8));
        }
        #pragma unroll
        for (int mi = 0; mi < 4; ++mi)
            #pragma unroll
            for (int ni = 0; ni < 8; ++ni)
                accE[mi][ni] = MFMA(a4[mi], b8[ni], accE[mi][ni]);
    }
    unsigned short* Eb = Ebf + (size_t)b*65536;
    #pragma unroll
    for (int mi = 0; mi < 4; ++mi)
        #pragma unroll
        for (int ni = 0; ni < 8; ++ni)
            #pragma unroll
            for (int j = 0; j < 4; ++j) {
                int o = wrW*64 + mi*16 + lg*4 + j;
                int cp = wcW*128 + ni*16 + lr;
                Eb[(size_t)o*256 + cp] = f2bf(accE[mi][ni][j]);
            }
    // f[o] = sum_kk W2[o,kk] tb[kk] + Wb[o]
    if (t < 256) {
        float s = 0.f;
        for (int kk = 0; kk < 128; ++kk)
            s += bf2f(Ss[(t*128 + kk) ^ ((t&7)<<3)]) * tbv[kk];
        fv[b*256 + t] = s + Wbv[t];
    }
}

// ================= kB3: BN stats  sum1 = E r + N f ; sum2 = diag(E S E^T) + 2 f (E r) + N f^2 ==============
__global__ __launch_bounds__(256) void kB3(
    const unsigned short* __restrict__ Ebf, const unsigned short* __restrict__ Sbf,
    const float* __restrict__ rv, const float* __restrict__ fv, float* __restrict__ stats)
{
    __shared__ __align__(16) unsigned short Es[64*256];  // 32 KB
    __shared__ float s2l[64];
    __shared__ float er4[256];
    int b = blockIdx.x >> 2, sl = blockIdx.x & 3, obase = sl*64;
    int t = threadIdx.x, lane = t & 63, wv = t >> 6, lr = lane & 15, lg = lane >> 4;
    const unsigned short* Eb = Ebf + (size_t)b*65536;
    const unsigned short* Sb = Sbf + (size_t)b*65536;

    for (int i = t; i < 2048; i += 256) {
        int row = i >> 5, c8 = (i & 31) * 8;
        u16x8 vv = *(const u16x8*)(Eb + (size_t)(obase + row)*256 + c8);
        *(u16x8*)&Es[(row*256 + c8) ^ ((row&7)<<3)] = vv;
    }
    if (t < 64) s2l[t] = 0.f;
    __syncthreads();

    f32x4 acc[4][4];
    #pragma unroll
    for (int i = 0; i < 4; ++i)
        #pragma unroll
        for (int j = 0; j < 4; ++j) acc[i][j] = (f32x4){0,0,0,0};
    #pragma unroll
    for (int ks = 0; ks < 8; ++ks) {
        bf16x8 a4[4], b4[4];
        #pragma unroll
        for (int mi = 0; mi < 4; ++mi) {
            int ol = mi*16 + lr;
            a4[mi] = __builtin_bit_cast(bf16x8, *(const u16x8*)&Es[(ol*256 + ks*32 + lg*8) ^ ((ol&7)<<3)]);
        }
        #pragma unroll
        for (int ni = 0; ni < 4; ++ni) {
            int c2 = wv*64 + ni*16 + lr;
            b4[ni] = __builtin_bit_cast(bf16x8, *(const u16x8*)(Sb + (size_t)c2*256 + ks*32 + lg*8));
        }
        #pragma unroll
        for (int mi = 0; mi < 4; ++mi)
            #pragma unroll
            for (int ni = 0; ni < 4; ++ni)
                acc[mi][ni] = MFMA(a4[mi], b4[ni], acc[mi][ni]);
    }
    #pragma unroll
    for (int mi = 0; mi < 4; ++mi)
        #pragma unroll
        for (int j = 0; j < 4; ++j) {
            int ol = mi*16 + lg*4 + j;
            float v = 0.f;
            #pragma unroll
            for (int ni = 0; ni < 4; ++ni) {
                int c2 = wv*64 + ni*16 + lr;
                v += acc[mi][ni][j] * bf2f(Es[(ol*256 + c2) ^ ((ol&7)<<3)]);
            }
            v += __shfl_xor(v, 1); v += __shfl_xor(v, 2);
            v += __shfl_xor(v, 4); v += __shfl_xor(v, 8);
            if (lr == 0) atomicAdd(&s2l[ol], v);
        }
    {
        int ol = t & 63, q = t >> 6;
        float p = 0.f;
        for (int c = q*64; c < q*64 + 64; ++c)
            p += bf2f(Es[(ol*256 + c) ^ ((ol&7)<<3)]) * rv[b*256 + c];
        er4[q*64 + ol] = p;
    }
    __syncthreads();
    if (t < 64) {
        float er = er4[t] + er4[64+t] + er4[128+t] + er4[192+t];
        float fo = fv[b*256 + obase + t];
        atomicAdd(&stats[obase + t], er + 4096.0f*fo);
        atomicAdd(&stats[256 + obase + t], s2l[t] + 2.0f*fo*er + 4096.0f*fo*fo);
    }
}

// ================= kF: out = (E x + f - mu)*gamma*rsqrt(var+eps) + beta + x =================
__global__ __launch_bounds__(512) void kF(
    const float* __restrict__ x, const unsigned short* __restrict__ Ebf,
    const float* __restrict__ fv, const float* __restrict__ stats,
    const float* __restrict__ gamma, const float* __restrict__ beta,
    float* __restrict__ out)
{
    __shared__ __align__(16) unsigned short Xs[128*256];  // 64 KB, [n][c] swizzled
    __shared__ float scale_l[256], shift_l[256];
    int b = blockIdx.x >> 5, n0 = (blockIdx.x & 31) * 128;
    int t = threadIdx.x, lane = t & 63, wv = t >> 6, lr = lane & 15, lg = lane >> 4;
    const float inv = 1.0f / 32768.0f;
    if (t < 256) {
        float mu  = stats[t] * inv;
        float var = stats[256 + t] * inv - mu*mu;
        float sc  = gamma[t] * rsqrtf(var + 1e-5f);
        scale_l[t] = sc;
        shift_l[t] = (fv[b*256 + t] - mu) * sc + beta[t];
    }
    {
        int nq = (t & 31) * 4, c0 = (t >> 5) * 4;
        const float* xb = x + (size_t)b*CIN*NN + n0 + nq;
        #pragma unroll
        for (int p = 0; p < 4; ++p) {
            int c = p*64 + c0;
            const float* xp = xb + (size_t)c*NN;
            float4 f0 = *(const float4*)(xp);
            float4 f1 = *(const float4*)(xp + NN);
            float4 f2 = *(const float4*)(xp + 2*NN);
            float4 f3 = *(const float4*)(xp + 3*NN);
            *(ushort4*)&Xs[(nq+0)*256 + (c ^ (((nq+0)&7)<<3))] = pack4(f0.x,f1.x,f2.x,f3.x);
            *(ushort4*)&Xs[(nq+1)*256 + (c ^ (((nq+1)&7)<<3))] = pack4(f0.y,f1.y,f2.y,f3.y);
            *(ushort4*)&Xs[(nq+2)*256 + (c ^ (((nq+2)&7)<<3))] = pack4(f0.z,f1.z,f2.z,f3.z);
            *(ushort4*)&Xs[(nq+3)*256 + (c ^ (((nq+3)&7)<<3))] = pack4(f0.w,f1.w,f2.w,f3.w);
        }
    }
    __syncthreads();

    int wn = wv >> 2, wo = wv & 3;     // 2n x 4o grid: tile 64n x 64o
    int nb = wn*64, ob = wo*64;
    const unsigned short* Eb = Ebf + (size_t)b*65536;
    f32x4 acc[4][4];
    #pragma unroll
    for (int i = 0; i < 4; ++i)
        #pragma unroll
        for (int j = 0; j < 4; ++j) acc[i][j] = (f32x4){0,0,0,0};

    #pragma unroll
    for (int ks = 0; ks < 8; ++ks) {
        bf16x8 xf[4], ef[4];
        #pragma unroll
        for (int ni = 0; ni < 4; ++ni) {
            int n = nb + ni*16 + lr;
            xf[ni] = __builtin_bit_cast(bf16x8, *(const u16x8*)&Xs[(n*256 + ks*32 + lg*8) ^ ((n&7)<<3)]);
        }
        #pragma unroll
        for (int oi = 0; oi < 4; ++oi) {
            int o = ob + oi*16 + lr;
            ef[oi] = __builtin_bit_cast(bf16x8, *(const u16x8*)(Eb + (size_t)o*256 + ks*32 + lg*8));
        }
        #pragma unroll
        for (int ni = 0; ni < 4; ++ni)
            #pragma unroll
            for (int oi = 0; oi < 4; ++oi)
                acc[ni][oi] = MFMA(xf[ni], ef[oi], acc[ni][oi]);
    }

    float* op = out + (size_t)b*CIN*NN;
    #pragma unroll
    for (int oi = 0; oi < 4; ++oi) {
        int o = ob + oi*16 + lr;
        float sc = scale_l[o], sh = shift_l[o];
        #pragma unroll
        for (int ni = 0; ni < 4; ++ni) {
            int nbase = nb + ni*16 + lg*4;
            float4 st;
            float* sp = &st.x;
            #pragma unroll
            for (int j = 0; j < 4; ++j) {
                int n = nbase + j;
                sp[j] = acc[ni][oi][j]*sc + sh + bf2f(Xs[(n*256 + o) ^ ((n&7)<<3)]);
            }
            *(float4*)(op + (size_t)o*NN + n0 + nbase) = st;
        }
    }
}

extern "C" void kernel_launch(void* const* d_in, const int* in_sizes, int n_in,
                              void* d_out, int out_size, void* d_ws, size_t ws_size,
                              hipStream_t stream)
{
    (void)in_sizes; (void)n_in; (void)out_size; (void)ws_size;
    const float* x     = (const float*)d_in[0];
    const float* gw    = (const float*)d_in[1];
    const float* gb    = (const float*)d_in[2];
    const float* tw    = (const float*)d_in[3];
    const float* tb    = (const float*)d_in[4];
    const float* pw    = (const float*)d_in[5];
    const float* pb    = (const float*)d_in[6];
    const float* Ww    = (const float*)d_in[7];
    const float* Wb    = (const float*)d_in[8];
    const float* gamma = (const float*)d_in[9];
    const float* beta  = (const float*)d_in[10];
    float* out = (float*)d_out;

    char* ws = (char*)d_ws;
    float* Sp            = (float*)(ws + 0);                   // 32 MB
    unsigned short* Sbf  = (unsigned short*)(ws + 33554432);   // 1 MB
    float* Rp            = (float*)(ws + 34603008);            // 128 KB
    float* rv            = (float*)(ws + 34734080);            // 8 KB
    unsigned short* Pwb  = (unsigned short*)(ws + 34742272);   // 64 KB
    unsigned short* Gwb  = (unsigned short*)(ws + 34807808);   // 64 KB
    unsigned short* TwT  = (unsigned short*)(ws + 34873344);   // 64 KB
    unsigned short* Wwb  = (unsigned short*)(ws + 34938880);   // 64 KB
    unsigned short* Ebf  = (unsigned short*)(ws + 35004416);   // 1 MB
    float* fv            = (float*)(ws + 36052992);            // 8 KB
    float* stats         = (float*)(ws + 36061184);            // 2 KB

    kA_gram<<<128, 512, 0, stream>>>(x, Sp, Rp);
    kR     <<<144, 256, 0, stream>>>(Sp, Rp, pw, gw, tw, Ww, Sbf, rv, Pwb, Gwb, TwT, Wwb, stats);
    kB12   <<<8,   512, 0, stream>>>(Sbf, rv, pw, gw, Pwb, Gwb, TwT, Wwb, gb, pb, tb, Wb, Ebf, fv);
    kB3    <<<32,  256, 0, stream>>>(Ebf, Sbf, rv, fv, stats);
    kF     <<<256, 512, 0, stream>>>(x, Ebf, fv, stats, gamma, beta, out);
}